// Round 8
// baseline (494.703 us; speedup 1.0000x reference)
//
#include <hip/hip_runtime.h>

typedef __bf16 v8bf __attribute__((ext_vector_type(8)));
typedef __bf16 v4bf __attribute__((ext_vector_type(4)));
typedef float  v4f  __attribute__((ext_vector_type(4)));

#define MFMA16x16x32 __builtin_amdgcn_mfma_f32_16x16x32_bf16

#define HIDDEN 128
#define NHEADS 8

// ---------------- K_A: prep_all — tables (0..63) + wswz (64..71) + hist + zero-out + pre ----------------
// r13: wswz's Wk half is pre-scaled by 0.25 (the 1/sqrt(16) softmax scale).
// Power-of-2 scaling commutes exactly with bf16 rounding -> bit-safe fold;
// edge kernel drops the per-score mul.
__global__ __launch_bounds__(512) void prep_all(
    const float* __restrict__ rel, const float* __restrict__ W1,
    const float* __restrict__ Wk, const float* __restrict__ Wv,
    const float* __restrict__ W2, const int* __restrict__ dst,
    int* __restrict__ count,
    __bf16* __restrict__ mlppre, __bf16* __restrict__ relbf,
    __bf16* __restrict__ wswz, __bf16* __restrict__ w2bf,
    float* __restrict__ outz,
    const float* __restrict__ x, const float* __restrict__ Wq,
    const float* __restrict__ bq, const float* __restrict__ b1,
    __bf16* __restrict__ qbf, __bf16* __restrict__ hpre, __bf16* __restrict__ xbf,
    int N, int E, int hb, int zb, int nz4)
{
  __shared__ __bf16 X[32][136];
  const int b = blockIdx.x;
  if (b < 64) {
    __shared__ float rrow[128];
    const int j = threadIdx.x;
    if (j < 128) rrow[j] = rel[b*HIDDEN + j];
    __syncthreads();
    if (j < 128) {
      float acc = W1[256*HIDDEN + j];            // w1r (tm row)
      #pragma unroll 4
      for (int k=0;k<128;k++) acc += rrow[k]*W1[(128+k)*HIDDEN + j];
      mlppre[b*HIDDEN + j] = (__bf16)acc;
      relbf [b*HIDDEN + j] = (__bf16)rrow[j];
    }
    return;
  }
  if (b < 72) {
    int f = (b - 64)*512 + threadIdx.x;
    if (f < 128) w2bf[f] = (__bf16)W2[f];
    if (f >= 2*8*4*64) return;
    int lane = f & 63, kk = (f>>6)&3, c = (f>>8)&7, mat = f>>11;
    const float* W = mat ? Wv : Wk;
    const float scl = mat ? 1.0f : 0.25f;        // fold softmax 1/sqrt(hd) into Wk
    int qq = lane>>4, nn = lane&15;
    v8bf o;
    #pragma unroll
    for (int j=0;j<8;j++) o[j] = (__bf16)(W[(kk*32 + qq*8 + j)*HIDDEN + c*16 + nn]*scl);
    *(v8bf*)(wswz + (long)f*8) = o;
    return;
  }
  if (b < 72 + hb) {
    // hist, int4-vectorized: 4 edges/thread
    long i = (long)(b - 72)*512 + threadIdx.x;
    long e4 = i*4;
    if (e4 + 3 < E) {
      int4 d = *(const int4*)(dst + e4);
      atomicAdd(&count[d.x], 1);
      atomicAdd(&count[d.y], 1);
      atomicAdd(&count[d.z], 1);
      atomicAdd(&count[d.w], 1);
    } else {
      for (long e = e4; e < E; e++) atomicAdd(&count[dst[e]], 1);
    }
    return;
  }
  if (b < 72 + hb + zb) {
    int idx = (b - 72 - hb)*512 + threadIdx.x;
    if (idx < nz4) ((float4*)outz)[idx] = make_float4(0.f,0.f,0.f,0.f);
    return;
  }
  // ---- pre: qbf = bf16(x@Wq+bq), hpre = bf16(x@W1a+b1), xbf = bf16(x) ----
  const int pb = b - (72 + hb + zb), npb = gridDim.x - (72 + hb + zb);
  const int tid = threadIdx.x;
  const int w = tid >> 6, l = tid & 63, qd = l >> 4, ln = l & 15;
  const int col = w*16 + ln;

  v8bf BQ[4], BH[4];
  #pragma unroll
  for (int kk=0; kk<4; kk++) {
    v8bf f, g;
    #pragma unroll
    for (int j=0;j<8;j++){
      f[j] = (__bf16)Wq[(kk*32 + qd*8 + j)*HIDDEN + col];
      g[j] = (__bf16)W1[(kk*32 + qd*8 + j)*HIDDEN + col];
    }
    BQ[kk] = f; BH[kk] = g;
  }
  const float bqv = bq[col], b1v = b1[col];

  const int s = tid >> 4, c8 = (tid & 15)*8;
  for (int n0 = pb*32; n0 < N; n0 += npb*32) {
    __syncthreads();
    int n = n0 + s;
    v8bf xv;
    if (n < N) {
      const float4* xp = (const float4*)(x + (long)n*HIDDEN + c8);
      float4 a = xp[0], b2_ = xp[1];
      xv[0]=(__bf16)a.x; xv[1]=(__bf16)a.y; xv[2]=(__bf16)a.z; xv[3]=(__bf16)a.w;
      xv[4]=(__bf16)b2_.x; xv[5]=(__bf16)b2_.y; xv[6]=(__bf16)b2_.z; xv[7]=(__bf16)b2_.w;
      *(v8bf*)(xbf + (long)n*HIDDEN + c8) = xv;
    } else {
      #pragma unroll
      for (int j=0;j<8;j++) xv[j] = (__bf16)0.f;
    }
    *(v8bf*)&X[s][c8] = xv;
    __syncthreads();

    v4f q0={0.f,0.f,0.f,0.f}, q1={0.f,0.f,0.f,0.f};
    v4f h0={0.f,0.f,0.f,0.f}, h1={0.f,0.f,0.f,0.f};
    #pragma unroll
    for (int kk=0;kk<4;kk++) {
      v8bf a0 = *(const v8bf*)&X[ln][kk*32 + qd*8];
      v8bf a1 = *(const v8bf*)&X[16+ln][kk*32 + qd*8];
      q0 = MFMA16x16x32(a0, BQ[kk], q0, 0,0,0);
      q1 = MFMA16x16x32(a1, BQ[kk], q1, 0,0,0);
      h0 = MFMA16x16x32(a0, BH[kk], h0, 0,0,0);
      h1 = MFMA16x16x32(a1, BH[kk], h1, 0,0,0);
    }
    #pragma unroll
    for (int r=0;r<4;r++) {
      int n_o = n0 + qd*4 + r;
      if (n_o < N) {
        qbf [(long)n_o*HIDDEN + col] = (__bf16)(q0[r] + bqv);
        hpre[(long)n_o*HIDDEN + col] = (__bf16)(h0[r] + b1v);
      }
      int n2 = n0 + 16 + qd*4 + r;
      if (n2 < N) {
        qbf [(long)n2*HIDDEN + col] = (__bf16)(q1[r] + bqv);
        hpre[(long)n2*HIDDEN + col] = (__bf16)(h1[r] + b1v);
      }
    }
  }
}

__global__ __launch_bounds__(1024) void scan_kernel(const int* __restrict__ count,
    int* __restrict__ base, int N)
{
  __shared__ int ssum[1024];
  const int t = threadIdx.x;
  const int chunk = ((N + 4095) >> 12) << 2;   // multiple of 4, chunk*1024 >= N
  const int lo = t*chunk, hi = min(lo + chunk, N);
  int s = 0;
  int i = lo;
  for (; i + 3 < hi; i += 4) {
    int4 v = *(const int4*)(count + i);
    s += v.x + v.y + v.z + v.w;
  }
  for (; i < hi; i++) s += count[i];
  ssum[t] = s;
  __syncthreads();
  #pragma unroll
  for (int ofs = 1; ofs < 1024; ofs <<= 1) {
    int v = (t >= ofs) ? ssum[t - ofs] : 0;
    __syncthreads();
    ssum[t] += v;
    __syncthreads();
  }
  int run = (t == 0) ? 0 : ssum[t-1];
  i = lo;
  for (; i + 3 < hi; i += 4) {
    int4 c = *(const int4*)(count + i);
    int4 o;
    o.x = run; o.y = run + c.x; o.z = o.y + c.y; o.w = o.z + c.z;
    *(int4*)(base + i) = o;
    run = o.w + c.w;
  }
  for (; i < hi; i++) { base[i] = run; run += count[i]; }
}

// ---------------- K_C: scat_dw — scatter + dw fused (8 edges/wave) ----------------
__global__ __launch_bounds__(512) void scat_dw(
    const int* __restrict__ src, const int* __restrict__ dstp,
    const int* __restrict__ etyp, const float* __restrict__ etime,
    const float* __restrict__ ts, const float* __restrict__ tc,
    const __bf16* __restrict__ hpre, const __bf16* __restrict__ mlppre,
    const __bf16* __restrict__ w2bf, const float* __restrict__ b2,
    const int* __restrict__ base, int* __restrict__ cursor,
    int4* __restrict__ meta4, int E)
{
  const int tid = threadIdx.x;
  const int wid = tid >> 6, l = tid & 63;
  const long e0 = ((long)blockIdx.x*8 + wid)*8;   // 8 edges per wave
  const int ei = l >> 3, lc = l & 7;              // edge-in-wave, 16-dim chunk

  int s_=0, d_=0, ty_=0; float et_=0.f, tsd_=0.f;
  if (l < 8 && e0 + l < E) {
    long e = e0 + l;
    s_ = src[e]; d_ = dstp[e]; ty_ = etyp[e]; et_ = etime[e]; tsd_ = ts[d_];
  }
  const int sE  = __shfl(s_, ei);
  const int dE  = __shfl(d_, ei);
  const int tyE = __shfl(ty_, ei);
  const float etE  = __shfl(et_, ei);
  const float tsdE = __shfl(tsd_, ei);

  const float invtc = 1.0f / (fabsf(tc[0]) + 1e-9f);
  const float dt = (tsdE - etE) * invtc;
  const float tm = 1.0f/(1.0f + __expf(-dt));

  const v8bf w2a = *(const v8bf*)(w2bf + lc*16);
  const v8bf w2b = *(const v8bf*)(w2bf + lc*16 + 8);
  const __bf16* hp = hpre  + (long)sE *HIDDEN + lc*16;
  const __bf16* mp = mlppre+ (long)tyE*HIDDEN + lc*16;
  v8bf av0 = *(const v8bf*)hp, av1 = *(const v8bf*)(hp + 8);
  v8bf bp0 = *(const v8bf*)mp, bp1 = *(const v8bf*)(mp + 8);

  float z = 0.f;
  #pragma unroll
  for (int j=0;j<8;j++){
    float p0 = (float)av0[j] + tm*(float)bp0[j];
    float p1 = (float)av1[j] + tm*(float)bp1[j];
    z += fmaxf(p0, 0.f)*(float)w2a[j] + fmaxf(p1, 0.f)*(float)w2b[j];
  }
  z += __shfl_xor(z,1); z += __shfl_xor(z,2); z += __shfl_xor(z,4);

  if (lc == 0 && e0 + ei < E) {
    float dw = 1.0f/(1.0f + __expf(-(z + b2[0])));
    int p = base[dE] + atomicAdd(&cursor[dE], 1);
    meta4[p] = make_int4(sE, dE, tyE, __float_as_int(tm * dw));
  }
}

// ---------------- K2 v13: WAVE-AUTONOMOUS edge kernel — zero per-tile barriers ----------------
// r13 evidence: edge is issue-rate limited (~1700 VALU cyc/wave-tile in a ~9100cy
// tile slot, VALUBusy 59% == 3.2 waves/SIMD issuing) because the 8-wave block
// convoys on the per-tile barrier that the LDS message round-trip requires.
// v13: ONE WAVE = ONE TILE. The wave computes its 32-edge message directly into
// MFMA A-fragment registers (lane l holds msg[edge b*16+ln][dim kk*32+qd*8+j] —
// exactly the layout ds_read was producing; 32 VGPR) and loops all 8 heads,
// reading K/V B-frags from a block-shared LDS weight copy (64KB, staged once,
// single barrier at start, 16B/lane contiguous = conflict-light). No per-tile
// barrier, no MSG LDS traffic, no 8x-duplicated segmask/meta work. q prefetched
// one head ahead (MFMA covers latency). Softmax 0.25 pre-folded into Wk/bk.
// Locality swizzle REVERTED (r12: contiguous ranges -7us vs strided).
__global__ __launch_bounds__(512, 4) void edge_fused7(
    const int4* __restrict__ meta4,
    const __bf16* __restrict__ xbf, const __bf16* __restrict__ qbf,
    const __bf16* __restrict__ relbf, const __bf16* __restrict__ wswz,
    const float* __restrict__ bk, const float* __restrict__ bv,
    float* __restrict__ out, float* __restrict__ denom, int E, int ntiles)
{
  __shared__ __align__(16) __bf16 W[32768];   // [mat][head][kk][lane][8] = 64KB
  __shared__ float sbk[128], sbv[128];

  const int tid = threadIdx.x;
  const int l = tid & 63, qd = l >> 4, ln = l & 15;

  // ---- stage weights to LDS (once) ----
  #pragma unroll
  for (int i=0;i<8;i++) {
    int o = (i*512 + tid)*8;
    *(v8bf*)&W[o] = *(const v8bf*)(wswz + o);
  }
  if (tid < 128) { sbk[tid] = bk[tid]*0.25f; sbv[tid] = bv[tid]; }
  __syncthreads();

  const int nwaves = gridDim.x * 8;
  const int w0 = blockIdx.x*8 + (tid >> 6);

  for (int t = w0; t < ntiles; t += nwaves) {
    // ---- meta ----
    int4 mt = make_int4(0, -1, 0, 0);
    { int e = t*32 + l; if (l < 32 && e < E) mt = meta4[e]; }
    const int d_m = mt.y;

    // ---- segment mask over dst runs (dst-sorted) ----
    int dprev = __shfl(d_m, (l>0)?(l-1):0);
    int flag = (l < 32) && ((l==0) || (d_m != dprev));
    unsigned long long segmask = __ballot(flag);

    int dC[2][4];
    #pragma unroll
    for (int b=0;b<2;b++)
      #pragma unroll
      for (int r=0;r<4;r++) dC[b][r] = __shfl(d_m, b*16 + qd*4 + r);

    // ---- message -> A-fragment registers (no LDS round-trip) ----
    v8bf msgf[2][4];
    #pragma unroll
    for (int b=0;b<2;b++){
      const int srcE = __shfl(mt.x, b*16 + ln);
      const int tyE  = __shfl(mt.z, b*16 + ln);
      const float sM = __int_as_float(__shfl(mt.w, b*16 + ln));
      const __bf16* xs = xbf   + (long)srcE*HIDDEN + qd*8;
      const __bf16* rs = relbf + (long)tyE *HIDDEN + qd*8;
      #pragma unroll
      for (int kk=0;kk<4;kk++){
        v8bf xv = *(const v8bf*)(xs + kk*32);
        v8bf rv = *(const v8bf*)(rs + kk*32);
        v8bf m;
        #pragma unroll
        for (int j=0;j<8;j++) m[j] = (__bf16)((float)xv[j]*(float)rv[j]*sM);
        msgf[b][kk] = m;
      }
    }

    // ---- q for head 0 ----
    float qv[2][4];
    #pragma unroll
    for (int b=0;b<2;b++)
      #pragma unroll
      for (int r=0;r<4;r++){
        int d = dC[b][r];
        qv[b][r] = (float)qbf[(long)(d<0?0:d)*HIDDEN + ln];
      }

    // ---- head loop: each wave does all 8 heads for its own tile ----
    #pragma unroll 1
    for (int c=0;c<8;c++){
      v4f aK0={0.f,0.f,0.f,0.f}, aK1={0.f,0.f,0.f,0.f};
      v4f aV0={0.f,0.f,0.f,0.f}, aV1={0.f,0.f,0.f,0.f};
      __builtin_amdgcn_s_setprio(1);
      #pragma unroll
      for (int kk=0;kk<4;kk++){
        v8bf bkf = *(const v8bf*)&W[        c*2048 + kk*512 + l*8];
        v8bf bvf = *(const v8bf*)&W[16384 + c*2048 + kk*512 + l*8];
        aK0 = MFMA16x16x32(msgf[0][kk], bkf, aK0, 0,0,0);
        aV0 = MFMA16x16x32(msgf[0][kk], bvf, aV0, 0,0,0);
        aK1 = MFMA16x16x32(msgf[1][kk], bkf, aK1, 0,0,0);
        aV1 = MFMA16x16x32(msgf[1][kk], bvf, aV1, 0,0,0);
      }
      __builtin_amdgcn_s_setprio(0);

      // prefetch q for head c+1 (latency hidden under reduce/flush)
      float qn[2][4];
      if (c < 7) {
        #pragma unroll
        for (int b=0;b<2;b++)
          #pragma unroll
          for (int r=0;r<4;r++){
            int d = dC[b][r];
            qn[b][r] = (float)qbf[(long)(d<0?0:d)*HIDDEN + (c+1)*16 + ln];
          }
      }

      const float bkc = sbk[c*16 + ln], bvc = sbv[c*16 + ln];
      float sc[2][4];
      #pragma unroll
      for (int r=0;r<4;r++){
        sc[0][r] = (aK0[r] + bkc)*qv[0][r];
        sc[1][r] = (aK1[r] + bkc)*qv[1][r];
      }
      #pragma unroll
      for (int m=1;m<16;m<<=1){
        #pragma unroll
        for (int b=0;b<2;b++)
          #pragma unroll
          for (int r=0;r<4;r++) sc[b][r] += __shfl_xor(sc[b][r], m);
      }
      float ee[2][4], wv[2][4];
      #pragma unroll
      for (int r=0;r<4;r++){
        float e0_ = __expf(sc[0][r]);          // 0.25 pre-folded into Wk/bk
        float e1_ = __expf(sc[1][r]);
        ee[0][r] = e0_; wv[0][r] = e0_*(aV0[r] + bvc);
        ee[1][r] = e1_; wv[1][r] = e1_*(aV1[r] + bvc);
      }

      // ---- segment flush ----
      unsigned long long mm = segmask;
      while (mm){
        int s0 = __ffsll((long long)mm) - 1;
        mm &= mm - 1;
        int s1 = mm ? (__ffsll((long long)mm) - 1) : 32;
        int dseg = __shfl(d_m, s0);
        if (dseg < 0) continue;
        float a0 = 0.f, dn0 = 0.f;
        #pragma unroll
        for (int b=0;b<2;b++)
          #pragma unroll
          for (int r=0;r<4;r++){
            int rw = b*16 + qd*4 + r;
            bool in = (rw >= s0) && (rw < s1);
            a0  += in ? wv[b][r] : 0.f;
            dn0 += in ? ee[b][r] : 0.f;
          }
        a0  += __shfl_xor(a0,16);  a0  += __shfl_xor(a0,32);
        dn0 += __shfl_xor(dn0,16); dn0 += __shfl_xor(dn0,32);
        if (l < 16) atomicAdd(&out[(long)dseg*HIDDEN + c*16 + ln], a0);
        if (l == 0) atomicAdd(&denom[(long)dseg*NHEADS + c], dn0);
      }

      if (c < 7) {
        #pragma unroll
        for (int b=0;b<2;b++)
          #pragma unroll
          for (int r=0;r<4;r++) qv[b][r] = qn[b][r];
      }
    }
  }
}

// ---------------- fallback: f32 q + round-1 atomic edge kernel ----------------
__global__ __launch_bounds__(512) void q_kernel(const float* __restrict__ x,
    const float* __restrict__ Wq, const float* __restrict__ bq,
    float* __restrict__ q, int N)
{
  __shared__ __bf16 X[32][136];
  const int tid = threadIdx.x;
  const int w = tid >> 6, l = tid & 63, qd = l >> 4, ln = l & 15;
  const int col = w*16 + ln;
  v8bf B[4];
  #pragma unroll
  for (int kk=0; kk<4; kk++) {
    v8bf f;
    #pragma unroll
    for (int j=0;j<8;j++) f[j] = (__bf16)Wq[(kk*32 + qd*8 + j)*HIDDEN + col];
    B[kk] = f;
  }
  const float bqv = bq[col];
  const int s = tid >> 4, c8 = (tid & 15)*8;
  for (int n0 = blockIdx.x*32; n0 < N; n0 += gridDim.x*32) {
    __syncthreads();
    int n = n0 + s;
    v8bf xv;
    if (n < N) {
      const float4* xp = (const float4*)(x + (long)n*HIDDEN + c8);
      float4 a = xp[0], b = xp[1];
      xv[0]=(__bf16)a.x; xv[1]=(__bf16)a.y; xv[2]=(__bf16)a.z; xv[3]=(__bf16)a.w;
      xv[4]=(__bf16)b.x; xv[5]=(__bf16)b.y; xv[6]=(__bf16)b.z; xv[7]=(__bf16)b.w;
    } else {
      #pragma unroll
      for (int j=0;j<8;j++) xv[j] = (__bf16)0.f;
    }
    *(v8bf*)&X[s][c8] = xv;
    __syncthreads();
    v4f acc0 = {0.f,0.f,0.f,0.f}, acc1 = {0.f,0.f,0.f,0.f};
    #pragma unroll
    for (int kk=0;kk<4;kk++) {
      v8bf a0 = *(const v8bf*)&X[ln][kk*32 + qd*8];
      v8bf a1 = *(const v8bf*)&X[16+ln][kk*32 + qd*8];
      acc0 = MFMA16x16x32(a0, B[kk], acc0, 0,0,0);
      acc1 = MFMA16x16x32(a1, B[kk], acc1, 0,0,0);
    }
    #pragma unroll
    for (int r=0;r<4;r++) {
      int n_o = n0 + qd*4 + r;
      if (n_o < N) q[(long)n_o*HIDDEN + col] = acc0[r] + bqv;
      int n_o2 = n0 + 16 + qd*4 + r;
      if (n_o2 < N) q[(long)n_o2*HIDDEN + col] = acc1[r] + bqv;
    }
  }
}

__global__ __launch_bounds__(512) void edge_atomic(
    const float* __restrict__ x, const float* __restrict__ ts,
    const int* __restrict__ src, const int* __restrict__ dst,
    const int* __restrict__ etyp, const float* __restrict__ etime,
    const float* __restrict__ rel,
    const float* __restrict__ Wk, const float* __restrict__ bk,
    const float* __restrict__ Wv, const float* __restrict__ bv,
    const float* __restrict__ W1, const float* __restrict__ b1,
    const float* __restrict__ W2, const float* __restrict__ b2,
    const float* __restrict__ tc,
    const float* __restrict__ qws, float* __restrict__ denom,
    float* __restrict__ out, int E)
{
  __shared__ __bf16 A[32][264];
  __shared__ __bf16 A2[32][136];
  __shared__ float sW2[128], sb1[128], sw1r[128], sbk[128], sbv[128];
  __shared__ float stm[32], sdw[32];
  __shared__ int   ssrc[32], sdst[32], styp[32];
  __shared__ float dwpart[8][32];
  const int tid = threadIdx.x;
  const int w = tid >> 6, l = tid & 63, qd = l >> 4, ln = l & 15;
  const int col = w*16 + ln;
  v8bf B1[8], BK[4], BV[4];
  #pragma unroll
  for (int kk=0;kk<8;kk++){ v8bf f;
    #pragma unroll
    for (int j=0;j<8;j++) f[j] = (__bf16)W1[(kk*32+qd*8+j)*HIDDEN + col];
    B1[kk]=f; }
  #pragma unroll
  for (int kk=0;kk<4;kk++){ v8bf f,g;
    #pragma unroll
    for (int j=0;j<8;j++){ f[j] = (__bf16)Wk[(kk*32+qd*8+j)*HIDDEN + col];
                           g[j] = (__bf16)Wv[(kk*32+qd*8+j)*HIDDEN + col]; }
    BK[kk]=f; BV[kk]=g; }
  if (tid < 128) {
    sW2[tid]=W2[tid]; sb1[tid]=b1[tid]; sw1r[tid]=W1[256*HIDDEN+tid];
    sbk[tid]=bk[tid]; sbv[tid]=bv[tid];
  }
  const float b2v = b2[0];
  const float invtc = 1.0f / (fabsf(tc[0]) + 1e-9f);
  const int s = tid >> 4, c8 = (tid & 15)*8;
  const int ntiles = (E + 31) >> 5;
  for (int t = blockIdx.x; t < ntiles; t += gridDim.x) {
    const int e0 = t*32;
    __syncthreads();
    if (tid < 32) {
      int e = e0 + tid;
      if (e < E) {
        int d = dst[e];
        ssrc[tid]=src[e]; sdst[tid]=d; styp[tid]=etyp[e];
        float dt = (ts[d] - etime[e]) * invtc;
        stm[tid] = 1.0f/(1.0f+expf(-dt));
      } else { ssrc[tid]=0; sdst[tid]=0; styp[tid]=0; stm[tid]=0.f; }
    }
    __syncthreads();
    {
      const float tmv = stm[s];
      const float4* xp = (const float4*)(x + (long)ssrc[s]*HIDDEN + c8);
      float4 a = xp[0], b = xp[1];
      const float4* rp = (const float4*)(rel + (long)styp[s]*HIDDEN + c8);
      float4 ra = rp[0], rb = rp[1];
      v8bf sv, rv;
      sv[0]=(__bf16)a.x; sv[1]=(__bf16)a.y; sv[2]=(__bf16)a.z; sv[3]=(__bf16)a.w;
      sv[4]=(__bf16)b.x; sv[5]=(__bf16)b.y; sv[6]=(__bf16)b.z; sv[7]=(__bf16)b.w;
      rv[0]=(__bf16)(ra.x*tmv); rv[1]=(__bf16)(ra.y*tmv);
      rv[2]=(__bf16)(ra.z*tmv); rv[3]=(__bf16)(ra.w*tmv);
      rv[4]=(__bf16)(rb.x*tmv); rv[5]=(__bf16)(rb.y*tmv);
      rv[6]=(__bf16)(rb.z*tmv); rv[7]=(__bf16)(rb.w*tmv);
      *(v8bf*)&A[s][c8] = sv;
      *(v8bf*)&A[s][128 + c8] = rv;
    }
    __syncthreads();
    v4f acc0={0.f,0.f,0.f,0.f}, acc1={0.f,0.f,0.f,0.f};
    #pragma unroll
    for (int kk=0;kk<8;kk++){
      v8bf a0 = *(const v8bf*)&A[ln][kk*32 + qd*8];
      v8bf a1 = *(const v8bf*)&A[16+ln][kk*32 + qd*8];
      acc0 = MFMA16x16x32(a0, B1[kk], acc0, 0,0,0);
      acc1 = MFMA16x16x32(a1, B1[kk], acc1, 0,0,0);
    }
    float part[8];
    {
      const float w1rj = sw1r[col], b1j = sb1[col], w2j = sW2[col];
      #pragma unroll
      for (int r=0;r<4;r++){
        int i0 = qd*4 + r, i1 = 16 + qd*4 + r;
        part[r]   = fmaxf(acc0[r] + stm[i0]*w1rj + b1j, 0.f)*w2j;
        part[4+r] = fmaxf(acc1[r] + stm[i1]*w1rj + b1j, 0.f)*w2j;
      }
    }
    #pragma unroll
    for (int m=1;m<16;m<<=1){
      #pragma unroll
      for (int i=0;i<8;i++) part[i] += __shfl_xor(part[i], m, 16);
    }
    if (ln == 0){
      #pragma unroll
      for (int r=0;r<4;r++){ dwpart[w][qd*4+r]=part[r]; dwpart[w][16+qd*4+r]=part[4+r]; }
    }
    __syncthreads();
    if (tid < 32){
      float z = b2v;
      #pragma unroll
      for (int ww=0;ww<8;ww++) z += dwpart[ww][tid];
      sdw[tid] = 1.0f/(1.0f+expf(-z));
    }
    __syncthreads();
    {
      const float dwv = sdw[s];
      v8bf mv;
      #pragma unroll
      for (int i=0;i<8;i++)
        mv[i] = (__bf16)((float)A[s][c8+i]*(float)A[s][128+c8+i]*dwv);
      *(v8bf*)&A2[s][c8] = mv;
    }
    __syncthreads();
    v4f k0={0.f,0.f,0.f,0.f}, k1={0.f,0.f,0.f,0.f};
    v4f v0={0.f,0.f,0.f,0.f}, v1={0.f,0.f,0.f,0.f};
    #pragma unroll
    for (int kk=0;kk<4;kk++){
      v8bf a0 = *(const v8bf*)&A2[ln][kk*32 + qd*8];
      v8bf a1 = *(const v8bf*)&A2[16+ln][kk*32 + qd*8];
      k0 = MFMA16x16x32(a0, BK[kk], k0, 0,0,0);
      k1 = MFMA16x16x32(a1, BK[kk], k1, 0,0,0);
      v0 = MFMA16x16x32(a0, BV[kk], v0, 0,0,0);
      v1 = MFMA16x16x32(a1, BV[kk], v1, 0,0,0);
    }
    float sc[8];
    const float bkj = sbk[col], bvj = sbv[col];
    #pragma unroll
    for (int r=0;r<4;r++){
      int i0 = qd*4 + r, i1 = 16 + qd*4 + r;
      sc[r]   = (k0[r]+bkj)*qws[(long)sdst[i0]*HIDDEN + col];
      sc[4+r] = (k1[r]+bkj)*qws[(long)sdst[i1]*HIDDEN + col];
    }
    #pragma unroll
    for (int m=1;m<16;m<<=1){
      #pragma unroll
      for (int i=0;i<8;i++) sc[i] += __shfl_xor(sc[i], m, 16);
    }
    float ee[8];
    #pragma unroll
    for (int i=0;i<8;i++) ee[i] = expf(sc[i]*0.25f);
    if (ln == 0){
      #pragma unroll
      for (int r=0;r<4;r++){
        int i0 = qd*4 + r, i1 = 16 + qd*4 + r;
        if (e0+i0 < E) atomicAdd(&denom[(long)sdst[i0]*NHEADS + w], ee[r]);
        if (e0+i1 < E) atomicAdd(&denom[(long)sdst[i1]*NHEADS + w], ee[4+r]);
      }
    }
    #pragma unroll
    for (int r=0;r<4;r++){
      int i0 = qd*4 + r, i1 = 16 + qd*4 + r;
      if (e0+i0 < E) atomicAdd(&out[(long)sdst[i0]*HIDDEN + col], ee[r]*(v0[r]+bvj));
      if (e0+i1 < E) atomicAdd(&out[(long)sdst[i1]*HIDDEN + col], ee[4+r]*(v1[r]+bvj));
    }
  }
}

// ---------------- K3: out /= denom ----------------
__global__ void fin_kernel(float* __restrict__ out, const float* __restrict__ denom, int N)
{
  int idx = blockIdx.x*blockDim.x + threadIdx.x;
  int total = N*32;
  if (idx < total){
    int n = idx >> 5;
    int h = (idx & 31) >> 2;
    float d = denom[n*8 + h];
    float inv = d > 0.f ? 1.0f/d : 0.f;
    float4* p = (float4*)out + idx;
    float4 v = *p;
    v.x*=inv; v.y*=inv; v.z*=inv; v.w*=inv;
    *p = v;
  }
}

static inline size_t align256(size_t v){ return (v + 255) & ~(size_t)255; }

extern "C" void kernel_launch(void* const* d_in, const int* in_sizes, int n_in,
                              void* d_out, int out_size, void* d_ws, size_t ws_size,
                              hipStream_t stream)
{
  const float* x      = (const float*)d_in[0];
  const float* ts     = (const float*)d_in[1];
  const int*   src    = (const int*)d_in[2];
  const int*   dstp   = (const int*)d_in[3];
  const int*   etyp   = (const int*)d_in[4];
  const float* etime  = (const float*)d_in[5];
  const float* rel    = (const float*)d_in[6];
  const float* Wq     = (const float*)d_in[7];
  const float* bq     = (const float*)d_in[8];
  const float* Wk     = (const float*)d_in[9];
  const float* bk     = (const float*)d_in[10];
  const float* Wv     = (const float*)d_in[11];
  const float* bv     = (const float*)d_in[12];
  const float* W1     = (const float*)d_in[13];
  const float* b1     = (const float*)d_in[14];
  const float* W2     = (const float*)d_in[15];
  const float* b2     = (const float*)d_in[16];
  const float* tc     = (const float*)d_in[17];
  float* out = (float*)d_out;

  const int N = in_sizes[0] / HIDDEN;
  const int E = in_sizes[2];

  char* ws = (char*)d_ws;
  size_t off = 0;
  __bf16* qbf    = (__bf16*)(ws + off); off += align256((size_t)N*HIDDEN*2);
  __bf16* hpre   = (__bf16*)(ws + off); off += align256((size_t)N*HIDDEN*2);
  __bf16* xbf    = (__bf16*)(ws + off); off += align256((size_t)N*HIDDEN*2);
  __bf16* relbf  = (__bf16*)(ws + off); off += align256((size_t)64*HIDDEN*2);
  __bf16* mlppre = (__bf16*)(ws + off); off += align256((size_t)64*HIDDEN*2);
  __bf16* w2bf   = (__bf16*)(ws + off); off += align256((size_t)HIDDEN*2);
  __bf16* wswz   = (__bf16*)(ws + off); off += align256((size_t)4096*8*2);
  // zero-span: countp, cursor, denom contiguous -> one memset
  size_t zoff = off;
  int*    countp = (int*)(ws + off);    off += align256((size_t)N*4);
  int*    cursor = (int*)(ws + off);    off += align256((size_t)N*4);
  float*  denom  = (float*)(ws + off);  off += align256((size_t)N*NHEADS*4);
  size_t zlen = off - zoff;
  int4*   meta4  = (int4*)(ws + off);   off += align256((size_t)E*16);
  int*    basep  = (int*)(ws + off);    off += align256((size_t)N*4);
  const size_t needed_fast = off;

  if (ws_size >= needed_fast) {
    hipMemsetAsync(ws + zoff, 0, zlen, stream);

    const int hb = (E + 2047)/2048;              // hist: 4 edges/thread, 512 thr
    const int nz4 = N*32;                        // float4 count of out
    const int zb = (nz4 + 511)/512;
    prep_all<<<72 + hb + zb + 1024, 512, 0, stream>>>(rel, W1, Wk, Wv, W2,
        dstp, countp, mlppre, relbf, wswz, w2bf, out,
        x, Wq, bq, b1, qbf, hpre, xbf, N, E, hb, zb, nz4);
    scan_kernel<<<1, 1024, 0, stream>>>(countp, basep, N);
    scat_dw<<<(E + 63)/64, 512, 0, stream>>>(src, dstp, etyp, etime, ts, tc,
        hpre, mlppre, w2bf, b2, basep, cursor, meta4, E);

    const int ntiles = (E + 31) >> 5;
    edge_fused7<<<1024, 512, 0, stream>>>(meta4,
        xbf, qbf, relbf, wswz, bk, bv, out, denom, E, ntiles);
    fin_kernel<<<(N*32 + 255)/256, 256, 0, stream>>>(out, denom, N);
  } else {
    // -------- fallback: round-1 atomic path --------
    float* qws    = (float*)ws;
    float* denom2 = (float*)(ws + align256((size_t)N*HIDDEN*4));
    hipMemsetAsync(out,    0, (size_t)N*HIDDEN*4, stream);
    hipMemsetAsync(denom2, 0, (size_t)N*NHEADS*4, stream);
    q_kernel<<<512, 512, 0, stream>>>(x, Wq, bq, qws, N);
    edge_atomic<<<512, 512, 0, stream>>>(x, ts, src, dstp, etyp, etime, rel,
        Wk, bk, Wv, bv, W1, b1, W2, b2, tc, qws, denom2, out, E);
    fin_kernel<<<(N*32 + 255)/256, 256, 0, stream>>>(out, denom2, N);
  }
}

// Round 9
// 451.172 us; speedup vs baseline: 1.0965x; 1.0965x over previous
//
#include <hip/hip_runtime.h>

typedef __bf16 v8bf __attribute__((ext_vector_type(8)));
typedef __bf16 v4bf __attribute__((ext_vector_type(4)));
typedef float  v4f  __attribute__((ext_vector_type(4)));

#define MFMA16x16x32 __builtin_amdgcn_mfma_f32_16x16x32_bf16

#define HIDDEN 128
#define NHEADS 8

// ---------------- K_A: prep_all — tables (0..63) + wswz (64..71) + hist + zero-out + pre ----------------
// wswz's Wk half pre-scaled by 0.25 (softmax 1/sqrt(16)); power-of-2 scale is
// bit-exact in bf16 -> edge kernel drops the per-score mul.
__global__ __launch_bounds__(512) void prep_all(
    const float* __restrict__ rel, const float* __restrict__ W1,
    const float* __restrict__ Wk, const float* __restrict__ Wv,
    const float* __restrict__ W2, const int* __restrict__ dst,
    int* __restrict__ count,
    __bf16* __restrict__ mlppre, __bf16* __restrict__ relbf,
    __bf16* __restrict__ wswz, __bf16* __restrict__ w2bf,
    float* __restrict__ outz,
    const float* __restrict__ x, const float* __restrict__ Wq,
    const float* __restrict__ bq, const float* __restrict__ b1,
    __bf16* __restrict__ qbf, __bf16* __restrict__ hpre, __bf16* __restrict__ xbf,
    int N, int E, int hb, int zb, int nz4)
{
  __shared__ __bf16 X[32][136];
  const int b = blockIdx.x;
  if (b < 64) {
    __shared__ float rrow[128];
    const int j = threadIdx.x;
    if (j < 128) rrow[j] = rel[b*HIDDEN + j];
    __syncthreads();
    if (j < 128) {
      float acc = W1[256*HIDDEN + j];            // w1r (tm row)
      #pragma unroll 4
      for (int k=0;k<128;k++) acc += rrow[k]*W1[(128+k)*HIDDEN + j];
      mlppre[b*HIDDEN + j] = (__bf16)acc;
      relbf [b*HIDDEN + j] = (__bf16)rrow[j];
    }
    return;
  }
  if (b < 72) {
    int f = (b - 64)*512 + threadIdx.x;
    if (f < 128) w2bf[f] = (__bf16)W2[f];
    if (f >= 2*8*4*64) return;
    int lane = f & 63, kk = (f>>6)&3, c = (f>>8)&7, mat = f>>11;
    const float* W = mat ? Wv : Wk;
    const float scl = mat ? 1.0f : 0.25f;        // fold softmax 1/sqrt(hd) into Wk
    int qq = lane>>4, nn = lane&15;
    v8bf o;
    #pragma unroll
    for (int j=0;j<8;j++) o[j] = (__bf16)(W[(kk*32 + qq*8 + j)*HIDDEN + c*16 + nn]*scl);
    *(v8bf*)(wswz + (long)f*8) = o;
    return;
  }
  if (b < 72 + hb) {
    // hist, int4-vectorized: 4 edges/thread
    long i = (long)(b - 72)*512 + threadIdx.x;
    long e4 = i*4;
    if (e4 + 3 < E) {
      int4 d = *(const int4*)(dst + e4);
      atomicAdd(&count[d.x], 1);
      atomicAdd(&count[d.y], 1);
      atomicAdd(&count[d.z], 1);
      atomicAdd(&count[d.w], 1);
    } else {
      for (long e = e4; e < E; e++) atomicAdd(&count[dst[e]], 1);
    }
    return;
  }
  if (b < 72 + hb + zb) {
    int idx = (b - 72 - hb)*512 + threadIdx.x;
    if (idx < nz4) ((float4*)outz)[idx] = make_float4(0.f,0.f,0.f,0.f);
    return;
  }
  // ---- pre: qbf = bf16(x@Wq+bq), hpre = bf16(x@W1a+b1), xbf = bf16(x) ----
  const int pb = b - (72 + hb + zb), npb = gridDim.x - (72 + hb + zb);
  const int tid = threadIdx.x;
  const int w = tid >> 6, l = tid & 63, qd = l >> 4, ln = l & 15;
  const int col = w*16 + ln;

  v8bf BQ[4], BH[4];
  #pragma unroll
  for (int kk=0; kk<4; kk++) {
    v8bf f, g;
    #pragma unroll
    for (int j=0;j<8;j++){
      f[j] = (__bf16)Wq[(kk*32 + qd*8 + j)*HIDDEN + col];
      g[j] = (__bf16)W1[(kk*32 + qd*8 + j)*HIDDEN + col];
    }
    BQ[kk] = f; BH[kk] = g;
  }
  const float bqv = bq[col], b1v = b1[col];

  const int s = tid >> 4, c8 = (tid & 15)*8;
  for (int n0 = pb*32; n0 < N; n0 += npb*32) {
    __syncthreads();
    int n = n0 + s;
    v8bf xv;
    if (n < N) {
      const float4* xp = (const float4*)(x + (long)n*HIDDEN + c8);
      float4 a = xp[0], b2_ = xp[1];
      xv[0]=(__bf16)a.x; xv[1]=(__bf16)a.y; xv[2]=(__bf16)a.z; xv[3]=(__bf16)a.w;
      xv[4]=(__bf16)b2_.x; xv[5]=(__bf16)b2_.y; xv[6]=(__bf16)b2_.z; xv[7]=(__bf16)b2_.w;
      *(v8bf*)(xbf + (long)n*HIDDEN + c8) = xv;
    } else {
      #pragma unroll
      for (int j=0;j<8;j++) xv[j] = (__bf16)0.f;
    }
    *(v8bf*)&X[s][c8] = xv;
    __syncthreads();

    v4f q0={0.f,0.f,0.f,0.f}, q1={0.f,0.f,0.f,0.f};
    v4f h0={0.f,0.f,0.f,0.f}, h1={0.f,0.f,0.f,0.f};
    #pragma unroll
    for (int kk=0;kk<4;kk++) {
      v8bf a0 = *(const v8bf*)&X[ln][kk*32 + qd*8];
      v8bf a1 = *(const v8bf*)&X[16+ln][kk*32 + qd*8];
      q0 = MFMA16x16x32(a0, BQ[kk], q0, 0,0,0);
      q1 = MFMA16x16x32(a1, BQ[kk], q1, 0,0,0);
      h0 = MFMA16x16x32(a0, BH[kk], h0, 0,0,0);
      h1 = MFMA16x16x32(a1, BH[kk], h1, 0,0,0);
    }
    #pragma unroll
    for (int r=0;r<4;r++) {
      int n_o = n0 + qd*4 + r;
      if (n_o < N) {
        qbf [(long)n_o*HIDDEN + col] = (__bf16)(q0[r] + bqv);
        hpre[(long)n_o*HIDDEN + col] = (__bf16)(h0[r] + b1v);
      }
      int n2 = n0 + 16 + qd*4 + r;
      if (n2 < N) {
        qbf [(long)n2*HIDDEN + col] = (__bf16)(q1[r] + bqv);
        hpre[(long)n2*HIDDEN + col] = (__bf16)(h1[r] + b1v);
      }
    }
  }
}

__global__ __launch_bounds__(1024) void scan_kernel(const int* __restrict__ count,
    int* __restrict__ base, int N)
{
  __shared__ int ssum[1024];
  const int t = threadIdx.x;
  const int chunk = ((N + 4095) >> 12) << 2;   // multiple of 4, chunk*1024 >= N
  const int lo = t*chunk, hi = min(lo + chunk, N);
  int s = 0;
  int i = lo;
  for (; i + 3 < hi; i += 4) {
    int4 v = *(const int4*)(count + i);
    s += v.x + v.y + v.z + v.w;
  }
  for (; i < hi; i++) s += count[i];
  ssum[t] = s;
  __syncthreads();
  #pragma unroll
  for (int ofs = 1; ofs < 1024; ofs <<= 1) {
    int v = (t >= ofs) ? ssum[t - ofs] : 0;
    __syncthreads();
    ssum[t] += v;
    __syncthreads();
  }
  int run = (t == 0) ? 0 : ssum[t-1];
  i = lo;
  for (; i + 3 < hi; i += 4) {
    int4 c = *(const int4*)(count + i);
    int4 o;
    o.x = run; o.y = run + c.x; o.z = o.y + c.y; o.w = o.z + c.z;
    *(int4*)(base + i) = o;
    run = o.w + c.w;
  }
  for (; i < hi; i++) { base[i] = run; run += count[i]; }
}

// ---------------- K_C: scat_dw — scatter + dw fused (8 edges/wave) ----------------
__global__ __launch_bounds__(512) void scat_dw(
    const int* __restrict__ src, const int* __restrict__ dstp,
    const int* __restrict__ etyp, const float* __restrict__ etime,
    const float* __restrict__ ts, const float* __restrict__ tc,
    const __bf16* __restrict__ hpre, const __bf16* __restrict__ mlppre,
    const __bf16* __restrict__ w2bf, const float* __restrict__ b2,
    const int* __restrict__ base, int* __restrict__ cursor,
    int4* __restrict__ meta4, int E)
{
  const int tid = threadIdx.x;
  const int wid = tid >> 6, l = tid & 63;
  const long e0 = ((long)blockIdx.x*8 + wid)*8;   // 8 edges per wave
  const int ei = l >> 3, lc = l & 7;              // edge-in-wave, 16-dim chunk

  int s_=0, d_=0, ty_=0; float et_=0.f, tsd_=0.f;
  if (l < 8 && e0 + l < E) {
    long e = e0 + l;
    s_ = src[e]; d_ = dstp[e]; ty_ = etyp[e]; et_ = etime[e]; tsd_ = ts[d_];
  }
  const int sE  = __shfl(s_, ei);
  const int dE  = __shfl(d_, ei);
  const int tyE = __shfl(ty_, ei);
  const float etE  = __shfl(et_, ei);
  const float tsdE = __shfl(tsd_, ei);

  const float invtc = 1.0f / (fabsf(tc[0]) + 1e-9f);
  const float dt = (tsdE - etE) * invtc;
  const float tm = 1.0f/(1.0f + __expf(-dt));

  const v8bf w2a = *(const v8bf*)(w2bf + lc*16);
  const v8bf w2b = *(const v8bf*)(w2bf + lc*16 + 8);
  const __bf16* hp = hpre  + (long)sE *HIDDEN + lc*16;
  const __bf16* mp = mlppre+ (long)tyE*HIDDEN + lc*16;
  v8bf av0 = *(const v8bf*)hp, av1 = *(const v8bf*)(hp + 8);
  v8bf bp0 = *(const v8bf*)mp, bp1 = *(const v8bf*)(mp + 8);

  float z = 0.f;
  #pragma unroll
  for (int j=0;j<8;j++){
    float p0 = (float)av0[j] + tm*(float)bp0[j];
    float p1 = (float)av1[j] + tm*(float)bp1[j];
    z += fmaxf(p0, 0.f)*(float)w2a[j] + fmaxf(p1, 0.f)*(float)w2b[j];
  }
  z += __shfl_xor(z,1); z += __shfl_xor(z,2); z += __shfl_xor(z,4);

  if (lc == 0 && e0 + ei < E) {
    float dw = 1.0f/(1.0f + __expf(-(z + b2[0])));
    int p = base[dE] + atomicAdd(&cursor[dE], 1);
    meta4[p] = make_int4(sE, dE, tyE, __float_as_int(tm * dw));
  }
}

// ---------------- K2 v14: RESTORED best edge kernel (= edge_fused5 + 0.25 fold) ----------------
// r14 evidence chain: v11 pipelined+barrier = 225us (best); v12 contiguous =
// 232 (atomic contention between same-block waves on shared dst rows beats the
// balance gain); v13 barrier-free but unpipelined = 285, VALUBusy 59->41 (the
// 1-tile-ahead prefetch, not the barrier, was carrying the kernel). Restore v11
// exactly: strided tiles, 1-ahead meta/row/q prefetch, single raw
// lgkmcnt-only barrier, double-buffered swizzled MSG. Only delta: softmax 0.25
// pre-folded into Wk/bk (bit-exact) -> expf(sc) directly.
__global__ __launch_bounds__(512, 4) void edge_fused8(
    const int4* __restrict__ meta4,
    const __bf16* __restrict__ xbf, const __bf16* __restrict__ qbf,
    const __bf16* __restrict__ relbf, const __bf16* __restrict__ wswz,
    const float* __restrict__ bk, const float* __restrict__ bv,
    float* __restrict__ out, float* __restrict__ denom, int E, int ntiles)
{
  __shared__ __align__(16) __bf16 MSG[2][4096];   // [2][32 rows][128], XOR-swizzled

  const int tid = threadIdx.x;
  const int wid = tid >> 6, l = tid & 63, qd = l >> 4, ln = l & 15;
  const int eIdx = wid*4 + qd;         // message: edge 0..31 (absolute in tile)

  // ---- pinned weights: this wave's head (=wid), K+V B-fragments (32 VGPRs) ----
  v8bf bkf[4], bvf[4];
  #pragma unroll
  for (int kk=0;kk<4;kk++){
    bkf[kk] = *(const v8bf*)(wswz +         wid*2048 + kk*512 + (size_t)l*8);
    bvf[kk] = *(const v8bf*)(wswz + 16384 + wid*2048 + kk*512 + (size_t)l*8);
  }
  const float bkc = bk[wid*16 + ln]*0.25f;   // fold matches pre-scaled Wk
  const float bvc = bv[wid*16 + ln];

  const int g = gridDim.x;
  int t = blockIdx.x;
  if (t >= ntiles) return;

  // ---- prologue: meta(t), meta(t+1), rows(t), q(t), dC(t) ----
  int4 mt = make_int4(0, -1, 0, 0);
  { int e = t*32 + l; if (l < 32 && e < E) mt = meta4[e]; }
  int tn = t + g;
  int4 mtn = make_int4(0, -1, 0, 0);
  if (tn < ntiles) { int e = tn*32 + l; if (l < 32 && e < E) mtn = meta4[e]; }

  float sME = __int_as_float(__shfl(mt.w, eIdx));
  v8bf sv, rv;
  {
    int srcE = __shfl(mt.x, eIdx);
    int tyE  = __shfl(mt.z, eIdx);
    sv = *(const v8bf*)(xbf   + (long)srcE*HIDDEN + ln*8);
    rv = *(const v8bf*)(relbf + (long)tyE *HIDDEN + ln*8);
  }
  int dC[2][4];
  #pragma unroll
  for (int b=0;b<2;b++)
    #pragma unroll
    for (int r=0;r<4;r++) dC[b][r] = __shfl(mt.y, b*16 + qd*4 + r);
  float qA[2][4];
  #pragma unroll
  for (int b=0;b<2;b++)
    #pragma unroll
    for (int r=0;r<4;r++){
      int d = dC[b][r];
      qA[b][r] = (float)qbf[(long)(d<0?0:d)*HIDDEN + wid*16 + ln];
    }

  int p = 0;
  while (true) {
    const int d_m = mt.y;

    // ---- segment mask over dst runs (dst-sorted) ----
    int dprev = __shfl(d_m, (l>0)?(l-1):0);
    int flag = (l < 32) && ((l==0) || (d_m != dprev));
    unsigned long long segmask = __ballot(flag);

    // ---- prefetch meta(t+2) ----
    const int t2 = tn + g;
    int4 mt2 = make_int4(0, -1, 0, 0);
    if (t2 < ntiles) { int e = t2*32 + l; if (l < 32 && e < E) mt2 = meta4[e]; }

    // ---- t+1 meta derived (mtn resident) ----
    const float sMN = __int_as_float(__shfl(mtn.w, eIdx));
    const int srcN = __shfl(mtn.x, eIdx);
    const int tyN  = __shfl(mtn.z, eIdx);
    int dN[2][4];
    #pragma unroll
    for (int b=0;b<2;b++)
      #pragma unroll
      for (int r=0;r<4;r++) dN[b][r] = __shfl(mtn.y, b*16 + qd*4 + r);

    // ---- message(t) -> swizzled LDS (one ds_write_b128/lane) ----
    {
      char* wbase = (char*)&MSG[p][0] + eIdx*256;
      const int sw = (eIdx & 7) << 4;
      v8bf m;
      #pragma unroll
      for (int j=0;j<8;j++) m[j] = (__bf16)((float)sv[j]*(float)rv[j]*sME);
      *(v8bf*)(wbase + ((ln*16) ^ sw)) = m;
    }

    // ---- prefetch rows(t+1) into the (now dead) row registers ----
    sv = *(const v8bf*)(xbf   + (long)srcN*HIDDEN + ln*8);
    rv = *(const v8bf*)(relbf + (long)tyN *HIDDEN + ln*8);

    // ---- prefetch q(t+1) ----
    float qB[2][4];
    #pragma unroll
    for (int b=0;b<2;b++)
      #pragma unroll
      for (int r=0;r<4;r++){
        int d = dN[b][r];
        qB[b][r] = (float)qbf[(long)(d<0?0:d)*HIDDEN + wid*16 + ln];
      }

    // ---- barrier: drain LDS writes only; global prefetches stay in flight ----
    asm volatile("s_waitcnt lgkmcnt(0)" ::: "memory");
    __builtin_amdgcn_s_barrier();
    __builtin_amdgcn_sched_barrier(0);

    // ---- MFMA: A from LDS, pinned B-frags (8 ds_read_b128, 8 MFMA) ----
    const char* rb = (const char*)&MSG[p][0];
    v4f aK[2], aV[2];
    __builtin_amdgcn_s_setprio(1);
    #pragma unroll
    for (int b=0;b<2;b++){
      const int rrow = b*16 + ln;
      const char* abase = rb + rrow*256;
      const int asw = (rrow & 7) << 4;
      v4f k_ = {0.f,0.f,0.f,0.f}, v_ = {0.f,0.f,0.f,0.f};
      #pragma unroll
      for (int kk=0;kk<4;kk++){
        v8bf a = *(const v8bf*)(abase + ((kk*64 + qd*16) ^ asw));
        k_ = MFMA16x16x32(a, bkf[kk], k_, 0,0,0);
        v_ = MFMA16x16x32(a, bvf[kk], v_, 0,0,0);
      }
      aK[b] = k_; aV[b] = v_;
    }
    __builtin_amdgcn_s_setprio(0);

    // ---- scores (0.25 pre-folded into Wk/bk) ----
    float sc[2][4];
    #pragma unroll
    for (int b=0;b<2;b++)
      #pragma unroll
      for (int r=0;r<4;r++) sc[b][r] = (aK[b][r] + bkc)*qA[b][r];
    #pragma unroll
    for (int m=1;m<16;m<<=1){
      #pragma unroll
      for (int b=0;b<2;b++)
        #pragma unroll
        for (int r=0;r<4;r++) sc[b][r] += __shfl_xor(sc[b][r], m);
    }
    float ee[2][4], wv[2][4];
    #pragma unroll
    for (int b=0;b<2;b++)
      #pragma unroll
      for (int r=0;r<4;r++){
        float e_ = __expf(sc[b][r]);
        ee[b][r] = e_;
        wv[b][r] = e_*(aV[b][r] + bvc);
      }

    // ---- segment flush (one head) ----
    unsigned long long mm = segmask;
    while (mm){
      int s0 = __ffsll((long long)mm) - 1;
      mm &= mm - 1;
      int s1 = mm ? (__ffsll((long long)mm) - 1) : 32;
      int dseg = __shfl(d_m, s0);
      if (dseg < 0) continue;
      float a0 = 0.f, dn0 = 0.f;
      #pragma unroll
      for (int b=0;b<2;b++)
        #pragma unroll
        for (int r=0;r<4;r++){
          int rw = b*16 + qd*4 + r;
          bool in = (rw >= s0) && (rw < s1);
          a0  += in ? wv[b][r] : 0.f;
          dn0 += in ? ee[b][r] : 0.f;
        }
      a0  += __shfl_xor(a0,16);  a0  += __shfl_xor(a0,32);
      dn0 += __shfl_xor(dn0,16); dn0 += __shfl_xor(dn0,32);
      if (l < 16) atomicAdd(&out[(long)dseg*HIDDEN + wid*16 + ln], a0);
      if (l == 0) atomicAdd(&denom[(long)dseg*NHEADS + wid], dn0);
    }

    if (tn >= ntiles) break;
    t = tn; tn = t2; mt = mtn; mtn = mt2; sME = sMN;
    #pragma unroll
    for (int b=0;b<2;b++)
      #pragma unroll
      for (int r=0;r<4;r++){
        dC[b][r] = dN[b][r];
        qA[b][r] = qB[b][r];
      }
    p ^= 1;
  }
}

// ---------------- fallback: f32 q + round-1 atomic edge kernel ----------------
__global__ __launch_bounds__(512) void q_kernel(const float* __restrict__ x,
    const float* __restrict__ Wq, const float* __restrict__ bq,
    float* __restrict__ q, int N)
{
  __shared__ __bf16 X[32][136];
  const int tid = threadIdx.x;
  const int w = tid >> 6, l = tid & 63, qd = l >> 4, ln = l & 15;
  const int col = w*16 + ln;
  v8bf B[4];
  #pragma unroll
  for (int kk=0; kk<4; kk++) {
    v8bf f;
    #pragma unroll
    for (int j=0;j<8;j++) f[j] = (__bf16)Wq[(kk*32 + qd*8 + j)*HIDDEN + col];
    B[kk] = f;
  }
  const float bqv = bq[col];
  const int s = tid >> 4, c8 = (tid & 15)*8;
  for (int n0 = blockIdx.x*32; n0 < N; n0 += gridDim.x*32) {
    __syncthreads();
    int n = n0 + s;
    v8bf xv;
    if (n < N) {
      const float4* xp = (const float4*)(x + (long)n*HIDDEN + c8);
      float4 a = xp[0], b = xp[1];
      xv[0]=(__bf16)a.x; xv[1]=(__bf16)a.y; xv[2]=(__bf16)a.z; xv[3]=(__bf16)a.w;
      xv[4]=(__bf16)b.x; xv[5]=(__bf16)b.y; xv[6]=(__bf16)b.z; xv[7]=(__bf16)b.w;
    } else {
      #pragma unroll
      for (int j=0;j<8;j++) xv[j] = (__bf16)0.f;
    }
    *(v8bf*)&X[s][c8] = xv;
    __syncthreads();
    v4f acc0 = {0.f,0.f,0.f,0.f}, acc1 = {0.f,0.f,0.f,0.f};
    #pragma unroll
    for (int kk=0;kk<4;kk++) {
      v8bf a0 = *(const v8bf*)&X[ln][kk*32 + qd*8];
      v8bf a1 = *(const v8bf*)&X[16+ln][kk*32 + qd*8];
      acc0 = MFMA16x16x32(a0, B[kk], acc0, 0,0,0);
      acc1 = MFMA16x16x32(a1, B[kk], acc1, 0,0,0);
    }
    #pragma unroll
    for (int r=0;r<4;r++) {
      int n_o = n0 + qd*4 + r;
      if (n_o < N) q[(long)n_o*HIDDEN + col] = acc0[r] + bqv;
      int n_o2 = n0 + 16 + qd*4 + r;
      if (n_o2 < N) q[(long)n_o2*HIDDEN + col] = acc1[r] + bqv;
    }
  }
}

__global__ __launch_bounds__(512) void edge_atomic(
    const float* __restrict__ x, const float* __restrict__ ts,
    const int* __restrict__ src, const int* __restrict__ dst,
    const int* __restrict__ etyp, const float* __restrict__ etime,
    const float* __restrict__ rel,
    const float* __restrict__ Wk, const float* __restrict__ bk,
    const float* __restrict__ Wv, const float* __restrict__ bv,
    const float* __restrict__ W1, const float* __restrict__ b1,
    const float* __restrict__ W2, const float* __restrict__ b2,
    const float* __restrict__ tc,
    const float* __restrict__ qws, float* __restrict__ denom,
    float* __restrict__ out, int E)
{
  __shared__ __bf16 A[32][264];
  __shared__ __bf16 A2[32][136];
  __shared__ float sW2[128], sb1[128], sw1r[128], sbk[128], sbv[128];
  __shared__ float stm[32], sdw[32];
  __shared__ int   ssrc[32], sdst[32], styp[32];
  __shared__ float dwpart[8][32];
  const int tid = threadIdx.x;
  const int w = tid >> 6, l = tid & 63, qd = l >> 4, ln = l & 15;
  const int col = w*16 + ln;
  v8bf B1[8], BK[4], BV[4];
  #pragma unroll
  for (int kk=0;kk<8;kk++){ v8bf f;
    #pragma unroll
    for (int j=0;j<8;j++) f[j] = (__bf16)W1[(kk*32+qd*8+j)*HIDDEN + col];
    B1[kk]=f; }
  #pragma unroll
  for (int kk=0;kk<4;kk++){ v8bf f,g;
    #pragma unroll
    for (int j=0;j<8;j++){ f[j] = (__bf16)Wk[(kk*32+qd*8+j)*HIDDEN + col];
                           g[j] = (__bf16)Wv[(kk*32+qd*8+j)*HIDDEN + col]; }
    BK[kk]=f; BV[kk]=g; }
  if (tid < 128) {
    sW2[tid]=W2[tid]; sb1[tid]=b1[tid]; sw1r[tid]=W1[256*HIDDEN+tid];
    sbk[tid]=bk[tid]; sbv[tid]=bv[tid];
  }
  const float b2v = b2[0];
  const float invtc = 1.0f / (fabsf(tc[0]) + 1e-9f);
  const int s = tid >> 4, c8 = (tid & 15)*8;
  const int ntiles = (E + 31) >> 5;
  for (int t = blockIdx.x; t < ntiles; t += gridDim.x) {
    const int e0 = t*32;
    __syncthreads();
    if (tid < 32) {
      int e = e0 + tid;
      if (e < E) {
        int d = dst[e];
        ssrc[tid]=src[e]; sdst[tid]=d; styp[tid]=etyp[e];
        float dt = (ts[d] - etime[e]) * invtc;
        stm[tid] = 1.0f/(1.0f+expf(-dt));
      } else { ssrc[tid]=0; sdst[tid]=0; styp[tid]=0; stm[tid]=0.f; }
    }
    __syncthreads();
    {
      const float tmv = stm[s];
      const float4* xp = (const float4*)(x + (long)ssrc[s]*HIDDEN + c8);
      float4 a = xp[0], b = xp[1];
      const float4* rp = (const float4*)(rel + (long)styp[s]*HIDDEN + c8);
      float4 ra = rp[0], rb = rp[1];
      v8bf sv, rv;
      sv[0]=(__bf16)a.x; sv[1]=(__bf16)a.y; sv[2]=(__bf16)a.z; sv[3]=(__bf16)a.w;
      sv[4]=(__bf16)b.x; sv[5]=(__bf16)b.y; sv[6]=(__bf16)b.z; sv[7]=(__bf16)b.w;
      rv[0]=(__bf16)(ra.x*tmv); rv[1]=(__bf16)(ra.y*tmv);
      rv[2]=(__bf16)(ra.z*tmv); rv[3]=(__bf16)(ra.w*tmv);
      rv[4]=(__bf16)(rb.x*tmv); rv[5]=(__bf16)(rb.y*tmv);
      rv[6]=(__bf16)(rb.z*tmv); rv[7]=(__bf16)(rb.w*tmv);
      *(v8bf*)&A[s][c8] = sv;
      *(v8bf*)&A[s][128 + c8] = rv;
    }
    __syncthreads();
    v4f acc0={0.f,0.f,0.f,0.f}, acc1={0.f,0.f,0.f,0.f};
    #pragma unroll
    for (int kk=0;kk<8;kk++){
      v8bf a0 = *(const v8bf*)&A[ln][kk*32 + qd*8];
      v8bf a1 = *(const v8bf*)&A[16+ln][kk*32 + qd*8];
      acc0 = MFMA16x16x32(a0, B1[kk], acc0, 0,0,0);
      acc1 = MFMA16x16x32(a1, B1[kk], acc1, 0,0,0);
    }
    float part[8];
    {
      const float w1rj = sw1r[col], b1j = sb1[col], w2j = sW2[col];
      #pragma unroll
      for (int r=0;r<4;r++){
        int i0 = qd*4 + r, i1 = 16 + qd*4 + r;
        part[r]   = fmaxf(acc0[r] + stm[i0]*w1rj + b1j, 0.f)*w2j;
        part[4+r] = fmaxf(acc1[r] + stm[i1]*w1rj + b1j, 0.f)*w2j;
      }
    }
    #pragma unroll
    for (int m=1;m<16;m<<=1){
      #pragma unroll
      for (int i=0;i<8;i++) part[i] += __shfl_xor(part[i], m, 16);
    }
    if (ln == 0){
      #pragma unroll
      for (int r=0;r<4;r++){ dwpart[w][qd*4+r]=part[r]; dwpart[w][16+qd*4+r]=part[4+r]; }
    }
    __syncthreads();
    if (tid < 32){
      float z = b2v;
      #pragma unroll
      for (int ww=0;ww<8;ww++) z += dwpart[ww][tid];
      sdw[tid] = 1.0f/(1.0f+expf(-z));
    }
    __syncthreads();
    {
      const float dwv = sdw[s];
      v8bf mv;
      #pragma unroll
      for (int i=0;i<8;i++)
        mv[i] = (__bf16)((float)A[s][c8+i]*(float)A[s][128+c8+i]*dwv);
      *(v8bf*)&A2[s][c8] = mv;
    }
    __syncthreads();
    v4f k0={0.f,0.f,0.f,0.f}, k1={0.f,0.f,0.f,0.f};
    v4f v0={0.f,0.f,0.f,0.f}, v1={0.f,0.f,0.f,0.f};
    #pragma unroll
    for (int kk=0;kk<4;kk++){
      v8bf a0 = *(const v8bf*)&A2[ln][kk*32 + qd*8];
      v8bf a1 = *(const v8bf*)&A2[16+ln][kk*32 + qd*8];
      k0 = MFMA16x16x32(a0, BK[kk], k0, 0,0,0);
      k1 = MFMA16x16x32(a1, BK[kk], k1, 0,0,0);
      v0 = MFMA16x16x32(a0, BV[kk], v0, 0,0,0);
      v1 = MFMA16x16x32(a1, BV[kk], v1, 0,0,0);
    }
    float sc[8];
    const float bkj = sbk[col], bvj = sbv[col];
    #pragma unroll
    for (int r=0;r<4;r++){
      int i0 = qd*4 + r, i1 = 16 + qd*4 + r;
      sc[r]   = (k0[r]+bkj)*qws[(long)sdst[i0]*HIDDEN + col];
      sc[4+r] = (k1[r]+bkj)*qws[(long)sdst[i1]*HIDDEN + col];
    }
    #pragma unroll
    for (int m=1;m<16;m<<=1){
      #pragma unroll
      for (int i=0;i<8;i++) sc[i] += __shfl_xor(sc[i], m, 16);
    }
    float ee[8];
    #pragma unroll
    for (int i=0;i<8;i++) ee[i] = expf(sc[i]*0.25f);
    if (ln == 0){
      #pragma unroll
      for (int r=0;r<4;r++){
        int i0 = qd*4 + r, i1 = 16 + qd*4 + r;
        if (e0+i0 < E) atomicAdd(&denom[(long)sdst[i0]*NHEADS + w], ee[r]);
        if (e0+i1 < E) atomicAdd(&denom[(long)sdst[i1]*NHEADS + w], ee[4+r]);
      }
    }
    #pragma unroll
    for (int r=0;r<4;r++){
      int i0 = qd*4 + r, i1 = 16 + qd*4 + r;
      if (e0+i0 < E) atomicAdd(&out[(long)sdst[i0]*HIDDEN + col], ee[r]*(v0[r]+bvj));
      if (e0+i1 < E) atomicAdd(&out[(long)sdst[i1]*HIDDEN + col], ee[4+r]*(v1[r]+bvj));
    }
  }
}

// ---------------- K3: out /= denom ----------------
__global__ void fin_kernel(float* __restrict__ out, const float* __restrict__ denom, int N)
{
  int idx = blockIdx.x*blockDim.x + threadIdx.x;
  int total = N*32;
  if (idx < total){
    int n = idx >> 5;
    int h = (idx & 31) >> 2;
    float d = denom[n*8 + h];
    float inv = d > 0.f ? 1.0f/d : 0.f;
    float4* p = (float4*)out + idx;
    float4 v = *p;
    v.x*=inv; v.y*=inv; v.z*=inv; v.w*=inv;
    *p = v;
  }
}

static inline size_t align256(size_t v){ return (v + 255) & ~(size_t)255; }

extern "C" void kernel_launch(void* const* d_in, const int* in_sizes, int n_in,
                              void* d_out, int out_size, void* d_ws, size_t ws_size,
                              hipStream_t stream)
{
  const float* x      = (const float*)d_in[0];
  const float* ts     = (const float*)d_in[1];
  const int*   src    = (const int*)d_in[2];
  const int*   dstp   = (const int*)d_in[3];
  const int*   etyp   = (const int*)d_in[4];
  const float* etime  = (const float*)d_in[5];
  const float* rel    = (const float*)d_in[6];
  const float* Wq     = (const float*)d_in[7];
  const float* bq     = (const float*)d_in[8];
  const float* Wk     = (const float*)d_in[9];
  const float* bk     = (const float*)d_in[10];
  const float* Wv     = (const float*)d_in[11];
  const float* bv     = (const float*)d_in[12];
  const float* W1     = (const float*)d_in[13];
  const float* b1     = (const float*)d_in[14];
  const float* W2     = (const float*)d_in[15];
  const float* b2     = (const float*)d_in[16];
  const float* tc     = (const float*)d_in[17];
  float* out = (float*)d_out;

  const int N = in_sizes[0] / HIDDEN;
  const int E = in_sizes[2];

  char* ws = (char*)d_ws;
  size_t off = 0;
  __bf16* qbf    = (__bf16*)(ws + off); off += align256((size_t)N*HIDDEN*2);
  __bf16* hpre   = (__bf16*)(ws + off); off += align256((size_t)N*HIDDEN*2);
  __bf16* xbf    = (__bf16*)(ws + off); off += align256((size_t)N*HIDDEN*2);
  __bf16* relbf  = (__bf16*)(ws + off); off += align256((size_t)64*HIDDEN*2);
  __bf16* mlppre = (__bf16*)(ws + off); off += align256((size_t)64*HIDDEN*2);
  __bf16* w2bf   = (__bf16*)(ws + off); off += align256((size_t)HIDDEN*2);
  __bf16* wswz   = (__bf16*)(ws + off); off += align256((size_t)4096*8*2);
  // zero-span: countp, cursor, denom contiguous -> one memset
  size_t zoff = off;
  int*    countp = (int*)(ws + off);    off += align256((size_t)N*4);
  int*    cursor = (int*)(ws + off);    off += align256((size_t)N*4);
  float*  denom  = (float*)(ws + off);  off += align256((size_t)N*NHEADS*4);
  size_t zlen = off - zoff;
  int4*   meta4  = (int4*)(ws + off);   off += align256((size_t)E*16);
  int*    basep  = (int*)(ws + off);    off += align256((size_t)N*4);
  const size_t needed_fast = off;

  if (ws_size >= needed_fast) {
    hipMemsetAsync(ws + zoff, 0, zlen, stream);

    const int hb = (E + 2047)/2048;              // hist: 4 edges/thread, 512 thr
    const int nz4 = N*32;                        // float4 count of out
    const int zb = (nz4 + 511)/512;
    prep_all<<<72 + hb + zb + 1024, 512, 0, stream>>>(rel, W1, Wk, Wv, W2,
        dstp, countp, mlppre, relbf, wswz, w2bf, out,
        x, Wq, bq, b1, qbf, hpre, xbf, N, E, hb, zb, nz4);
    scan_kernel<<<1, 1024, 0, stream>>>(countp, basep, N);
    scat_dw<<<(E + 63)/64, 512, 0, stream>>>(src, dstp, etyp, etime, ts, tc,
        hpre, mlppre, w2bf, b2, basep, cursor, meta4, E);

    const int ntiles = (E + 31) >> 5;
    edge_fused8<<<1024, 512, 0, stream>>>(meta4,
        xbf, qbf, relbf, wswz, bk, bv, out, denom, E, ntiles);
    fin_kernel<<<(N*32 + 255)/256, 256, 0, stream>>>(out, denom, N);
  } else {
    // -------- fallback: round-1 atomic path --------
    float* qws    = (float*)ws;
    float* denom2 = (float*)(ws + align256((size_t)N*HIDDEN*4));
    hipMemsetAsync(out,    0, (size_t)N*HIDDEN*4, stream);
    hipMemsetAsync(denom2, 0, (size_t)N*NHEADS*4, stream);
    q_kernel<<<512, 512, 0, stream>>>(x, Wq, bq, qws, N);
    edge_atomic<<<512, 512, 0, stream>>>(x, ts, src, dstp, etyp, etime, rel,
        Wk, bk, Wv, bv, W1, b1, W2, b2, tc, qws, denom2, out, E);
    fin_kernel<<<(N*32 + 255)/256, 256, 0, stream>>>(out, denom2, N);
  }
}